// Round 1
// baseline (36.542 us; speedup 1.0000x reference)
//
#include <hip/hip_runtime.h>
#include <math.h>

#define NHEAD 4
#define DD 100
#define WW 40
#define NW 39            // number of word rows
#define ALPHA 0.3f
#define BLOCK 256

__global__ __launch_bounds__(BLOCK) void ts_encoder_kernel(
    const float* __restrict__ x,       // [4800][40][100]
    const float* __restrict__ w_att,   // [4][100]
    const float* __restrict__ b_att,   // [4][100]
    float* __restrict__ out)           // [4800][400]
{
    __shared__ float tile[WW * DD];        // 4000 floats: row0 = type_emb, rows 1..39 = words
    __shared__ float wlds[NHEAD * DD];     // 400
    __shared__ float blds[NHEAD * DD];     // 400
    __shared__ float att[NHEAD][NW + 1];   // softmax weights (pad to avoid bank aliasing)

    const int site = blockIdx.x;
    const int tid  = threadIdx.x;

    // ---- stage w_att / b_att ----
    for (int i = tid; i < NHEAD * DD; i += BLOCK) {
        wlds[i] = w_att[i];
        blds[i] = b_att[i];
    }

    // ---- stage x tile (float4, fully coalesced; 1000 float4s) ----
    const float4* xs = (const float4*)(x + (size_t)site * (WW * DD));
    float4* ts = (float4*)tile;
    int local_nz = 0;
    #pragma unroll
    for (int i = 0; i < 4; ++i) {
        int idx = tid + i * BLOCK;
        if (idx < (WW * DD) / 4) {
            float4 v = xs[idx];
            ts[idx] = v;
            local_nz |= (v.x != 0.f) | (v.y != 0.f) | (v.z != 0.f) | (v.w != 0.f);
        }
    }
    const int nz = __syncthreads_or(local_nz);

    // ---- Phase A: scores.  wave = head, lane = word index n ----
    const int head = tid >> 6;
    const int lane = tid & 63;

    float sc = -INFINITY;
    if (lane < NW) {
        const float* wr = tile + (1 + lane) * DD;   // words row n
        const float* te = tile;                     // type_emb (broadcast)
        const float* wh = wlds + head * DD;         // broadcast within wave
        const float* bh = blds + head * DD;
        float acc = 0.f;
        #pragma unroll
        for (int d0 = 0; d0 < DD; d0 += 4) {
            float4 a  = *(const float4*)(wr + d0);
            float4 t  = *(const float4*)(te + d0);
            float4 wv = *(const float4*)(wh + d0);
            float4 bv = *(const float4*)(bh + d0);
            float p;
            p = fmaf(a.x, wv.x, bv.x); p = (p >= 0.f) ? p : ALPHA * p; acc = fmaf(t.x, p, acc);
            p = fmaf(a.y, wv.y, bv.y); p = (p >= 0.f) ? p : ALPHA * p; acc = fmaf(t.y, p, acc);
            p = fmaf(a.z, wv.z, bv.z); p = (p >= 0.f) ? p : ALPHA * p; acc = fmaf(t.z, p, acc);
            p = fmaf(a.w, wv.w, bv.w); p = (p >= 0.f) ? p : ALPHA * p; acc = fmaf(t.w, p, acc);
        }
        sc = acc;
    }

    // ---- Phase B: per-head softmax over n (wave64 shuffle reduce; stable) ----
    float mx = sc;
    #pragma unroll
    for (int off = 32; off > 0; off >>= 1) mx = fmaxf(mx, __shfl_xor(mx, off));
    float p = (lane < NW) ? __expf(sc - mx) : 0.f;
    float sm = p;
    #pragma unroll
    for (int off = 32; off > 0; off >>= 1) sm += __shfl_xor(sm, off);
    if (lane < NW) att[head][lane] = p / sm;
    __syncthreads();

    // ---- Phase C: out[h][d] = sum_n att[h][n] * words[n][d] ----
    float* osite = out + (size_t)site * (NHEAD * DD);
    if (nz) {
        #pragma unroll
        for (int pass = 0; pass < 2; ++pass) {
            int o = tid + pass * BLOCK;
            if (o < NHEAD * DD) {
                int h = o / DD;
                int d = o - h * DD;
                const float* col = tile + DD + d;   // words row 0, col d
                const float* ah  = att[h];
                float acc = 0.f;
                #pragma unroll
                for (int n = 0; n < NW; ++n)
                    acc = fmaf(ah[n], col[n * DD], acc);
                osite[o] = acc;
            }
        }
    } else {
        #pragma unroll
        for (int pass = 0; pass < 2; ++pass) {
            int o = tid + pass * BLOCK;
            if (o < NHEAD * DD) osite[o] = 0.f;
        }
    }
}

extern "C" void kernel_launch(void* const* d_in, const int* in_sizes, int n_in,
                              void* d_out, int out_size, void* d_ws, size_t ws_size,
                              hipStream_t stream) {
    const float* x     = (const float*)d_in[0];
    const float* w_att = (const float*)d_in[1];
    const float* b_att = (const float*)d_in[2];
    float* out = (float*)d_out;

    const int sites = 8 * 30 * 20;   // 4800
    ts_encoder_kernel<<<sites, BLOCK, 0, stream>>>(x, w_att, b_att, out);
}

// Round 2
// 32.019 us; speedup vs baseline: 1.1413x; 1.1413x over previous
//
#include <hip/hip_runtime.h>
#include <math.h>
#include <stdint.h>

#define NHEAD 4
#define DD 100
#define NW 39            // word rows
#define BLOCK 256
#define ALPHA 0.3f

typedef __attribute__((address_space(3))) uint32_t lds_t;
typedef const __attribute__((address_space(1))) uint32_t glb_t;

__global__ __launch_bounds__(BLOCK, 6) void ts_enc(
    const float* __restrict__ x,       // [4800][40][100]
    const float* __restrict__ w_att,   // [4][100]
    const float* __restrict__ b_att,   // [4][100]
    float* __restrict__ out)           // [4800][400]
{
    __shared__ float tile[40 * DD];          // 16000 B, row0 = type_emb
    __shared__ float sc_part[4][40][4];      // [wave][n][head] partial scores
    __shared__ float att_T[40][4];           // [n][head]
    __shared__ float pcs[NHEAD][4][25][4];   // [h][ngroup][dchunk][4]

    const int tid  = threadIdx.x;
    const int wv   = __builtin_amdgcn_readfirstlane(tid >> 6);  // wave id 0..3 (SGPR)
    const int lane = tid & 63;
    const float* xsite = x + (size_t)blockIdx.x * (40 * DD);

    // ---- stage tile: async global->LDS, 16 B per lane, 1000 float4 chunks ----
    #pragma unroll
    for (int i = 0; i < 4; ++i) {
        const int cf = i * BLOCK + tid;           // chunk index 0..1023
        if (cf < 1000) {
            glb_t* g = (glb_t*)(xsite + cf * 4);
            lds_t* l = (lds_t*)(tile + (i * BLOCK + wv * 64) * 4); // wave-uniform base
            __builtin_amdgcn_global_load_lds(g, l, 16, 0, 0);
        }
    }
    __syncthreads();

    // ---- Phase A: scores, d-split across waves, lane = n, all heads per pass ----
    // te / w_att / b_att come from global (wave-uniform addresses -> scalar/L1 pipe),
    // words come from LDS (one b128 per chunk, read once per block).
    const bool act = (lane < NW);
    const float* wrow = tile + (1 + lane) * DD;
    float acc[NHEAD] = {0.f, 0.f, 0.f, 0.f};

    for (int c = wv; c < 25; c += 4) {          // wave wv owns chunks wv, wv+4, ...
        const float4 te4 = *(const float4*)(xsite + c * 4);
        float4 v4 = make_float4(0.f, 0.f, 0.f, 0.f);
        if (act) v4 = *(const float4*)(wrow + c * 4);

        #pragma unroll
        for (int h = 0; h < NHEAD; ++h) {
            const float4 w4 = *(const float4*)(w_att + h * DD + c * 4);
            const float4 b4 = *(const float4*)(b_att + h * DD + c * 4);
            float p0 = fmaf(v4.x, w4.x, b4.x);
            float p1 = fmaf(v4.y, w4.y, b4.y);
            float p2 = fmaf(v4.z, w4.z, b4.z);
            float p3 = fmaf(v4.w, w4.w, b4.w);
            p0 = fmaxf(p0, 0.f) + ALPHA * fminf(p0, 0.f);   // leaky, exact
            p1 = fmaxf(p1, 0.f) + ALPHA * fminf(p1, 0.f);
            p2 = fmaxf(p2, 0.f) + ALPHA * fminf(p2, 0.f);
            p3 = fmaxf(p3, 0.f) + ALPHA * fminf(p3, 0.f);
            float d = fmaf(te4.x, p0, fmaf(te4.y, p1, fmaf(te4.z, p2, te4.w * p3)));
            acc[h] += d;
        }
    }
    if (act)
        *(float4*)&sc_part[wv][lane][0] = make_float4(acc[0], acc[1], acc[2], acc[3]);
    __syncthreads();

    // ---- Phase B: softmax over n; wave wv = head wv, lane = n ----
    float sc = -INFINITY;
    if (act)
        sc = sc_part[0][lane][wv] + sc_part[1][lane][wv]
           + sc_part[2][lane][wv] + sc_part[3][lane][wv];
    float mx = sc;
    #pragma unroll
    for (int off = 32; off; off >>= 1) mx = fmaxf(mx, __shfl_xor(mx, off));
    float p = act ? __expf(sc - mx) : 0.f;
    float sm = p;
    #pragma unroll
    for (int off = 32; off; off >>= 1) sm += __shfl_xor(sm, off);
    if (act) att_T[lane][wv] = p / sm;
    __syncthreads();

    // ---- Phase C part 1: out partials; thread=(ngroup,dchunk), words read once for all heads ----
    if (tid < 100) {
        const int ng = tid / 25;
        const int dc = tid - ng * 25;
        const int n0 = ng * 10;
        const int n1 = (ng == 3) ? NW : n0 + 10;
        float4 ac0 = {0,0,0,0}, ac1 = {0,0,0,0}, ac2 = {0,0,0,0}, ac3 = {0,0,0,0};
        const float* cb = tile + DD + dc * 4;    // words row 0, this d-chunk
        for (int n = n0; n < n1; ++n) {
            const float4 wd = *(const float4*)(cb + n * DD);
            const float4 at = *(const float4*)&att_T[n][0];  // att of all 4 heads at n
            ac0.x = fmaf(at.x, wd.x, ac0.x); ac0.y = fmaf(at.x, wd.y, ac0.y);
            ac0.z = fmaf(at.x, wd.z, ac0.z); ac0.w = fmaf(at.x, wd.w, ac0.w);
            ac1.x = fmaf(at.y, wd.x, ac1.x); ac1.y = fmaf(at.y, wd.y, ac1.y);
            ac1.z = fmaf(at.y, wd.z, ac1.z); ac1.w = fmaf(at.y, wd.w, ac1.w);
            ac2.x = fmaf(at.z, wd.x, ac2.x); ac2.y = fmaf(at.z, wd.y, ac2.y);
            ac2.z = fmaf(at.z, wd.z, ac2.z); ac2.w = fmaf(at.z, wd.w, ac2.w);
            ac3.x = fmaf(at.w, wd.x, ac3.x); ac3.y = fmaf(at.w, wd.y, ac3.y);
            ac3.z = fmaf(at.w, wd.z, ac3.z); ac3.w = fmaf(at.w, wd.w, ac3.w);
        }
        *(float4*)&pcs[0][ng][dc][0] = ac0;
        *(float4*)&pcs[1][ng][dc][0] = ac1;
        *(float4*)&pcs[2][ng][dc][0] = ac2;
        *(float4*)&pcs[3][ng][dc][0] = ac3;
    }
    __syncthreads();

    // ---- Phase C part 2: combine n-group partials, store ----
    if (tid < 100) {
        const int h  = tid / 25;
        const int dc = tid - h * 25;
        const float4 q0 = *(const float4*)&pcs[h][0][dc][0];
        const float4 q1 = *(const float4*)&pcs[h][1][dc][0];
        const float4 q2 = *(const float4*)&pcs[h][2][dc][0];
        const float4 q3 = *(const float4*)&pcs[h][3][dc][0];
        float4 r;
        r.x = (q0.x + q1.x) + (q2.x + q3.x);
        r.y = (q0.y + q1.y) + (q2.y + q3.y);
        r.z = (q0.z + q1.z) + (q2.z + q3.z);
        r.w = (q0.w + q1.w) + (q2.w + q3.w);
        *(float4*)(out + (size_t)blockIdx.x * (NHEAD * DD) + h * DD + dc * 4) = r;
    }
}

extern "C" void kernel_launch(void* const* d_in, const int* in_sizes, int n_in,
                              void* d_out, int out_size, void* d_ws, size_t ws_size,
                              hipStream_t stream) {
    const float* x     = (const float*)d_in[0];
    const float* w_att = (const float*)d_in[1];
    const float* b_att = (const float*)d_in[2];
    float* out = (float*)d_out;

    const int sites = 8 * 30 * 20;   // 4800
    ts_enc<<<sites, BLOCK, 0, stream>>>(x, w_att, b_att, out);
}